// Round 3
// baseline (499.139 us; speedup 1.0000x reference)
//
#include <hip/hip_runtime.h>
#include <math.h>

// GMM per-pixel sampling: out = mu[k] + exp(log_std[k]) * eps,
// k = #(cdf < u), cdf = cumsum(softmax(pi_logits)) over K=10 (innermost).
// Shapes [B,F,T,K] = [16,256,1024,10]; rows are 40 B.
//
// R5 structure: LDS transpose (coalesced global) + HIGH OCCUPANCY + overlap.
// History: R2/R3 (80 B-stride divergent loads, ~64 line-requests/instr) pinned
// at ~155 us at 80% occupancy -> TA/L2 request-path bound. R4 (coalesced via
// 30 KB LDS staging) pinned at 163 us at 25% occupancy -> concurrency-starved,
// bursty. This round holds BOTH: coalesced 16 B-lane-stride staging AND
// 16 waves/CU, with the mu/log_std stage loads issued BEFORE the softmax
// chain so their latency hides under ~800 cycles of VALU.
//  - LDS cut 30 KB -> 20 KB/block: buffer A is reused (pi tile, then mu tile);
//    log_std goes to buffer B. 8 blocks/CU * 20,480 B = 163,840 B = exactly
//    the 160 KiB LDS pool -> LDS-bound at 16 waves/CU (2x R4).
//  - __launch_bounds__(128,4) caps VGPR at 128 so LDS stays binding.
//  - ds_read_b128 at stride-80: lanes l, l+8 alias banks (20*8=160==0 mod 32)
//    -> 2-way within a 16-lane phase = free (m136). 4 B gathers ~conflict-free.
//  - All staging indices compile-time after unroll (rule #20, no scratch).
//
// Numerics mirror the JAX reference op-for-op (identical to passing R2/R4):
// e_j = expf(l_j - max); S = sum(e) in order; cdf += e_j / S (per-element
// IEEE divide, no hoisted reciprocal); strict cdf < u; k clipped to K-1.

#define KMIX 10
#define TPB 128                                   // 2 waves per block
#define PX_PER_BLOCK (TPB * 2)                    // 256 pixels per block
#define F_PER_ARRAY (PX_PER_BLOCK * KMIX)         // 2560 floats = 10,240 B
#define F4_PER_ARRAY (F_PER_ARRAY / 4)            // 640 float4

__device__ __forceinline__ int compute_k(const float* lt, float uval) {
    float m = lt[0];
    #pragma unroll
    for (int j = 1; j < KMIX; ++j) m = fmaxf(m, lt[j]);

    float e[KMIX];
    float S = 0.f;
    #pragma unroll
    for (int j = 0; j < KMIX; ++j) {
        e[j] = expf(lt[j] - m);
        S += e[j];
    }

    float cdf = 0.f;
    int k = 0;
    #pragma unroll
    for (int j = 0; j < KMIX; ++j) {
        cdf += e[j] / S;            // per-element IEEE divide, matches reference
        k += (cdf < uval) ? 1 : 0;  // strict compare, matches reference
    }
    return (k > KMIX - 1) ? (KMIX - 1) : k;   // jnp.clip(k, 0, K-1)
}

__global__ __launch_bounds__(TPB, 4) void gmm_sample_kernel(
    const float* __restrict__ mu,
    const float* __restrict__ log_std,
    const float* __restrict__ pi_logits,
    const float* __restrict__ u_cat,
    const float* __restrict__ eps,
    float* __restrict__ out,
    int npairs)
{
    // Buffer A holds the pi tile, then is REUSED for the mu tile.
    // Buffer B holds the log_std tile. 2 x 10,240 B = 20,480 B/block.
    __shared__ float4 sA[F4_PER_ARRAY];
    __shared__ float4 sB[F4_PER_ARRAY];

    const int tid = threadIdx.x;
    const size_t blk = blockIdx.x;
    const size_t base_f4 = blk * F4_PER_ARRAY;    // float4 index of block tile

    const float4* gpi = reinterpret_cast<const float4*>(pi_logits) + base_f4;
    const float4* gmu = reinterpret_cast<const float4*>(mu)        + base_f4;
    const float4* gls = reinterpret_cast<const float4*>(log_std)   + base_f4;

    // ---- Phase 1: stage pi tile, coalesced (16 B lane stride).
    float4 tp[5];
    #pragma unroll
    for (int j = 0; j < 5; ++j) tp[j] = gpi[j * TPB + tid];

    const size_t pair = blk * TPB + tid;          // pixel-pair index
    float2 uu = reinterpret_cast<const float2*>(u_cat)[pair];
    float2 ee = reinterpret_cast<const float2*>(eps)[pair];

    #pragma unroll
    for (int j = 0; j < 5; ++j) sA[j * TPB + tid] = tp[j];
    __syncthreads();

    // ---- Phase 2: issue mu/log_std stage loads NOW, then do the long
    // softmax/divide chain while they are in flight (latency hidden).
    float4 tm[5], tl[5];
    #pragma unroll
    for (int j = 0; j < 5; ++j) tm[j] = gmu[j * TPB + tid];
    #pragma unroll
    for (int j = 0; j < 5; ++j) tl[j] = gls[j * TPB + tid];

    // Own row-pair from LDS: 80 B = 5 x ds_read_b128 at stride-80.
    float l[2 * KMIX];
    #pragma unroll
    for (int j = 0; j < 5; ++j) {
        float4 a = sA[tid * 5 + j];
        l[4 * j + 0] = a.x; l[4 * j + 1] = a.y;
        l[4 * j + 2] = a.z; l[4 * j + 3] = a.w;
    }

    int k0 = compute_k(l, uu.x);
    int k1 = compute_k(l + KMIX, uu.y);

    __syncthreads();                   // everyone done reading pi from A

    // ---- Phase 3: land mu into A, log_std into B.
    #pragma unroll
    for (int j = 0; j < 5; ++j) sA[j * TPB + tid] = tm[j];
    #pragma unroll
    for (int j = 0; j < 5; ++j) sB[j * TPB + tid] = tl[j];
    __syncthreads();

    // ---- Phase 4: component gather from LDS (4 B reads, ~conflict-free).
    const float* s_mu = reinterpret_cast<const float*>(sA);
    const float* s_ls = reinterpret_cast<const float*>(sB);
    float mk0 = s_mu[20 * tid + k0];
    float sk0 = s_ls[20 * tid + k0];
    float mk1 = s_mu[20 * tid + KMIX + k1];
    float sk1 = s_ls[20 * tid + KMIX + k1];

    float2 r;
    r.x = mk0 + expf(sk0) * ee.x;
    r.y = mk1 + expf(sk1) * ee.y;
    if (pair < (size_t)npairs)
        reinterpret_cast<float2*>(out)[pair] = r;
}

extern "C" void kernel_launch(void* const* d_in, const int* in_sizes, int n_in,
                              void* d_out, int out_size, void* d_ws, size_t ws_size,
                              hipStream_t stream) {
    const float* mu        = (const float*)d_in[0];
    const float* log_std   = (const float*)d_in[1];
    const float* pi_logits = (const float*)d_in[2];
    const float* u_cat     = (const float*)d_in[3];
    const float* eps       = (const float*)d_in[4];
    float* out = (float*)d_out;

    int N = in_sizes[3];              // B*F*T = 4,194,304
    int npairs = N / 2;               // 2,097,152 = 16384 * 128 (exact blocks)
    int grid = (npairs + TPB - 1) / TPB;
    gmm_sample_kernel<<<grid, TPB, 0, stream>>>(mu, log_std, pi_logits,
                                                u_cat, eps, out, npairs);
}

// Round 4
// 454.097 us; speedup vs baseline: 1.0992x; 1.0992x over previous
//
#include <hip/hip_runtime.h>
#include <math.h>
#include <stdint.h>

// GMM per-pixel sampling: out = mu[k] + exp(log_std[k]) * eps,
// k = #(cdf < u), cdf = cumsum(softmax(pi_logits)) over K=10 (innermost).
// Shapes [B,F,T,K] = [16,256,1024,10]; rows are 40 B.
//
// R6 structure: R5's coalesced LDS-transpose staging, but via
// __builtin_amdgcn_global_load_lds (direct HBM->LDS DMA) so NO registers hold
// staged data. R5's post-mortem: WRITE_SIZE 16->344 MB = tm/tl (10 float4 =
// 160 B/thread) spilled to scratch when held across a barrier under the
// 128-VGPR cap; yet R5 proved this coalesced/42%-occupancy regime streams at
// 3.77 TB/s. R6 keeps that regime and removes the 335 MB of scratch traffic:
//  - 20 KB LDS/block (A: pi then mu; B: log_std) -> 8 blocks/CU = 16 waves/CU.
//  - Phase 1: DMA pi->A and log_std->B together (one round trip), plus u/eps
//    register loads. Phase 2: softmax/cdf from A, gather log_std[k] from B.
//    Phase 3: DMA mu->A (second trip; overlapped across the 8 resident
//    blocks/CU, and expf(log_std[k]) computed under it), gather mu[k], store.
//  - DMA dest is wave-uniform base + lane*16 (dest byte = 2048j + 16*tid =
//    (2048j + 1024*waveid) + lane*16): satisfies the global_load_lds linear-
//    dest rule. Source is the same affine float4 stream as R4/R5.
//  - ds_read_b128 at stride-80: lanes l, l+8 alias banks (20*8 mod 32 == 0)
//    -> 2-way per 16-lane phase = free (m136). 4 B gathers ~conflict-free.
//  - Grid is exact: npairs = 2,097,152 = 16384 * 128 -> no partial blocks,
//    so no OOB DMA.
//
// Numerics mirror the JAX reference op-for-op (identical to passing R2/R4/R5):
// e_j = expf(l_j - max); S = sum(e) in order; cdf += e_j / S (per-element
// IEEE divide, no hoisted reciprocal); strict cdf < u; k clipped to K-1.

#define KMIX 10
#define TPB 128                                   // 2 waves per block
#define F4_PER_ARRAY 640                          // 128 pairs * 80 B / 16 B

__device__ __forceinline__ void gload_lds16(const float4* g, float4* l) {
    __builtin_amdgcn_global_load_lds(
        (const __attribute__((address_space(1))) void*)g,
        (__attribute__((address_space(3))) void*)l,
        16, 0, 0);
}

__device__ __forceinline__ int compute_k(const float* lt, float uval) {
    float m = lt[0];
    #pragma unroll
    for (int j = 1; j < KMIX; ++j) m = fmaxf(m, lt[j]);

    float e[KMIX];
    float S = 0.f;
    #pragma unroll
    for (int j = 0; j < KMIX; ++j) {
        e[j] = expf(lt[j] - m);
        S += e[j];
    }

    float cdf = 0.f;
    int k = 0;
    #pragma unroll
    for (int j = 0; j < KMIX; ++j) {
        cdf += e[j] / S;            // per-element IEEE divide, matches reference
        k += (cdf < uval) ? 1 : 0;  // strict compare, matches reference
    }
    return (k > KMIX - 1) ? (KMIX - 1) : k;   // jnp.clip(k, 0, K-1)
}

__global__ __launch_bounds__(TPB, 4) void gmm_sample_kernel(
    const float* __restrict__ mu,
    const float* __restrict__ log_std,
    const float* __restrict__ pi_logits,
    const float* __restrict__ u_cat,
    const float* __restrict__ eps,
    float* __restrict__ out,
    int npairs)
{
    // A: pi tile, later reused for mu tile. B: log_std tile. 20,480 B total.
    __shared__ float4 sA[F4_PER_ARRAY];
    __shared__ float4 sB[F4_PER_ARRAY];

    const int tid = threadIdx.x;
    const size_t blk = blockIdx.x;
    const size_t base_f4 = blk * F4_PER_ARRAY;

    const float4* gpi = reinterpret_cast<const float4*>(pi_logits) + base_f4;
    const float4* gmu = reinterpret_cast<const float4*>(mu)        + base_f4;
    const float4* gls = reinterpret_cast<const float4*>(log_std)   + base_f4;

    // ---- Phase 1: DMA pi->A and log_std->B, one burst, zero staged VGPRs.
    #pragma unroll
    for (int j = 0; j < 5; ++j) gload_lds16(gpi + j * TPB + tid, &sA[j * TPB + tid]);
    #pragma unroll
    for (int j = 0; j < 5; ++j) gload_lds16(gls + j * TPB + tid, &sB[j * TPB + tid]);

    const size_t pair = blk * TPB + tid;          // pixel-pair index
    float2 uu = reinterpret_cast<const float2*>(u_cat)[pair];
    float2 ee = reinterpret_cast<const float2*>(eps)[pair];

    asm volatile("s_waitcnt vmcnt(0)" ::: "memory");
    __syncthreads();

    // ---- Phase 2: own row-pair from LDS (5 x ds_read_b128 at stride-80).
    float l[2 * KMIX];
    #pragma unroll
    for (int j = 0; j < 5; ++j) {
        float4 a = sA[tid * 5 + j];
        l[4 * j + 0] = a.x; l[4 * j + 1] = a.y;
        l[4 * j + 2] = a.z; l[4 * j + 3] = a.w;
    }

    int k0 = compute_k(l, uu.x);
    int k1 = compute_k(l + KMIX, uu.y);

    // log_std gather from B (B is never overwritten).
    const float* s_ls = reinterpret_cast<const float*>(sB);
    float sk0 = s_ls[20 * tid + k0];
    float sk1 = s_ls[20 * tid + KMIX + k1];

    __syncthreads();                   // all reads of pi tile in A complete

    // ---- Phase 3: DMA mu->A; hide its latency under the expf of log_std.
    #pragma unroll
    for (int j = 0; j < 5; ++j) gload_lds16(gmu + j * TPB + tid, &sA[j * TPB + tid]);

    float t0 = expf(sk0) * ee.x;
    float t1 = expf(sk1) * ee.y;

    asm volatile("s_waitcnt vmcnt(0)" ::: "memory");
    __syncthreads();

    const float* s_mu = reinterpret_cast<const float*>(sA);
    float mk0 = s_mu[20 * tid + k0];
    float mk1 = s_mu[20 * tid + KMIX + k1];

    float2 r;
    r.x = mk0 + t0;
    r.y = mk1 + t1;
    if (pair < (size_t)npairs)
        reinterpret_cast<float2*>(out)[pair] = r;
}

extern "C" void kernel_launch(void* const* d_in, const int* in_sizes, int n_in,
                              void* d_out, int out_size, void* d_ws, size_t ws_size,
                              hipStream_t stream) {
    const float* mu        = (const float*)d_in[0];
    const float* log_std   = (const float*)d_in[1];
    const float* pi_logits = (const float*)d_in[2];
    const float* u_cat     = (const float*)d_in[3];
    const float* eps       = (const float*)d_in[4];
    float* out = (float*)d_out;

    int N = in_sizes[3];              // B*F*T = 4,194,304
    int npairs = N / 2;               // 2,097,152 = 16384 * 128 (exact blocks)
    int grid = (npairs + TPB - 1) / TPB;
    gmm_sample_kernel<<<grid, TPB, 0, stream>>>(mu, log_std, pi_logits,
                                                u_cat, eps, out, npairs);
}